// Round 1
// baseline (402.700 us; speedup 1.0000x reference)
//
#include <hip/hip_runtime.h>
#include <hip/hip_bf16.h>
#include <math.h>

#define NV 8192
#define NE 2048
#define CIN 128
#define COUT 128
#define NH 4
#define HID 32
#define MAXDEG 256
#define EPSV 1e-5f

__device__ __forceinline__ float gelu_f(float x) {
    return 0.5f * x * (1.0f + erff(x * 0.70710678118654752f));
}
__device__ __forceinline__ float sigmoid_f(float x) {
    return 1.0f / (1.0f + expf(-x));
}

// ---------------- Kernel 1: Xt = X@Wv+bv ; attn[h,v] = sigmoid(gelu(X@vW1+vb1)@vW2+vb2)
__global__ __launch_bounds__(128) void k_vertex1(
    const float* __restrict__ X, const float* __restrict__ Wv, const float* __restrict__ bv,
    const float* __restrict__ vW1, const float* __restrict__ vb1,
    const float* __restrict__ vW2, const float* __restrict__ vb2,
    float* __restrict__ Xt, float* __restrict__ attn4)
{
    const int VPB = 8;
    __shared__ float Xs[VPB][CIN];
    int t = threadIdx.x;
    int v0 = blockIdx.x * VPB;
    for (int v = 0; v < VPB; ++v) Xs[v][t] = X[(v0 + v) * CIN + t];
    __syncthreads();

    float acc[VPB];
    float bvc = bv[t];
#pragma unroll
    for (int v = 0; v < VPB; ++v) acc[v] = bvc;
    for (int k = 0; k < CIN; ++k) {
        float w = Wv[k * COUT + t];
#pragma unroll
        for (int v = 0; v < VPB; ++v) acc[v] = fmaf(Xs[v][k], w, acc[v]);
    }
    for (int v = 0; v < VPB; ++v) Xt[(v0 + v) * COUT + t] = acc[v];

    // per-head MLP: thread t -> (head h, hidden j)
    int h = t >> 5, j = t & 31;
    float hb = vb1[h * HID + j];
#pragma unroll
    for (int v = 0; v < VPB; ++v) acc[v] = hb;
    for (int k = 0; k < CIN; ++k) {
        float w = vW1[(h * CIN + k) * HID + j];
#pragma unroll
        for (int v = 0; v < VPB; ++v) acc[v] = fmaf(Xs[v][k], w, acc[v]);
    }
    float w2 = vW2[h * HID + j];
    float b2 = vb2[h];
    for (int v = 0; v < VPB; ++v) {
        float val = gelu_f(acc[v]) * w2;
#pragma unroll
        for (int m = 16; m >= 1; m >>= 1) val += __shfl_xor(val, m, 64);
        if (j == 0) attn4[(v0 + v) * NH + h] = sigmoid_f(val + b2);
    }
}

// ---------------- Kernel 2: build per-edge vertex lists + degree counts from dense H
__global__ __launch_bounds__(256) void k_build(
    const float* __restrict__ H, int* __restrict__ cnt, int* __restrict__ elist)
{
    int idx4 = (blockIdx.x * 256 + threadIdx.x) * 4;
    float4 h4 = *(const float4*)(H + idx4);
    int v = idx4 >> 11;          // E = 2048
    int ebase = idx4 & (NE - 1);
    float hv[4] = {h4.x, h4.y, h4.z, h4.w};
#pragma unroll
    for (int i = 0; i < 4; ++i) {
        if (hv[i] != 0.0f) {
            int e = ebase + i;
            int p = atomicAdd(&cnt[e], 1);
            if (p < MAXDEG) elist[e * MAXDEG + p] = v;
        }
    }
}

// ---------------- Kernel 3: per-edge aggregation + combine + gating + LN (pre-BN)
__global__ __launch_bounds__(256) void k_edge(
    const float* __restrict__ Xt, const float* __restrict__ attn4,
    const int* __restrict__ cnt, const int* __restrict__ elist,
    const float* __restrict__ edge_features,
    const float* __restrict__ Wc, const float* __restrict__ bc,
    const float* __restrict__ We, const float* __restrict__ be,
    const float* __restrict__ eW1, const float* __restrict__ eb1,
    const float* __restrict__ eW2, const float* __restrict__ eb2,
    const float* __restrict__ ln_g, const float* __restrict__ ln_b,
    float* __restrict__ e_ln, float* __restrict__ out_att)
{
    __shared__ float ecat[2][NH * COUT];
    __shared__ float ef_lds[2][COUT];
    __shared__ float efr[2][COUT];
    __shared__ float redA[2][COUT], redB[2][COUT];
    __shared__ float ews[2];
    int t = threadIdx.x;
    int g = t >> 7;
    int c = t & 127;
    int e = blockIdx.x * 2 + g;

    efr[g][c] = edge_features[e * COUT + c];

    int n = cnt[e];
    float denom = fmaxf((float)n, 1.0f);
    if (n > MAXDEG) n = MAXDEG;
    float a0 = 0, a1 = 0, a2 = 0, a3 = 0, attsum = 0;
    const int* lst = elist + e * MAXDEG;
    for (int i = 0; i < n; ++i) {
        int v = lst[i];
        float x = Xt[v * COUT + c];
        float4 a = *(const float4*)(attn4 + v * NH);
        a0 = fmaf(x, a.x, a0);
        a1 = fmaf(x, a.y, a1);
        a2 = fmaf(x, a.z, a2);
        a3 = fmaf(x, a.w, a3);
        attsum += a.w;
    }
    float inv = 1.0f / denom;
    ecat[g][0 * COUT + c] = a0 * inv;
    ecat[g][1 * COUT + c] = a1 * inv;
    ecat[g][2 * COUT + c] = a2 * inv;
    ecat[g][3 * COUT + c] = a3 * inv;
    __syncthreads();

    // e_feat = e_cat @ Wc + bc
    float ef = bc[c];
    for (int k = 0; k < NH * COUT; ++k) ef = fmaf(ecat[g][k], Wc[k * COUT + c], ef);
    ef_lds[g][c] = ef;
    __syncthreads();

    // edge score MLP on PRE-blend e_feat
    if (c < 32) {
        float hj = eb1[c];
        for (int k = 0; k < COUT; ++k) hj = fmaf(ef_lds[g][k], eW1[k * HID + c], hj);
        float val = gelu_f(hj) * eW2[c];
#pragma unroll
        for (int m = 16; m >= 1; m >>= 1) val += __shfl_xor(val, m, 64);
        if (c == 0) ews[g] = sigmoid_f(val + eb2[0]);
    }
    __syncthreads();
    float ew = ews[g];

    // te = edge_features @ We + be
    float te = be[c];
    for (int k = 0; k < COUT; ++k) te = fmaf(efr[g][k], We[k * COUT + c], te);

    float x = ef * ew + te * (1.0f - ew);

    // LayerNorm over 128 channels
    redA[g][c] = x;
    redB[g][c] = x * x;
    __syncthreads();
    for (int s = 64; s >= 1; s >>= 1) {
        if (c < s) { redA[g][c] += redA[g][c + s]; redB[g][c] += redB[g][c + s]; }
        __syncthreads();
    }
    float m = redA[g][0] * (1.0f / COUT);
    float var = redB[g][0] * (1.0f / COUT) - m * m;
    float y = (x - m) * rsqrtf(var + EPSV) * ln_g[c] + ln_b[c];
    e_ln[e * COUT + c] = y;
    if (c == 0) out_att[e] = attsum * inv;
}

// ---------------- Kernel 4: BN stats over edges (per channel)
__global__ __launch_bounds__(128) void k_bnstats(const float* __restrict__ e_ln,
    float* __restrict__ bn_sum, float* __restrict__ bn_sq)
{
    int c = threadIdx.x;
    int e0 = blockIdx.x * 64;
    float s = 0, q = 0;
    for (int i = 0; i < 64; ++i) {
        float x = e_ln[(e0 + i) * COUT + c];
        s += x;
        q += x * x;
    }
    atomicAdd(&bn_sum[c], s);
    atomicAdd(&bn_sq[c], q);
}

// ---------------- Kernel 5: BN apply + e_feat output (gelu)
__global__ __launch_bounds__(256) void k_bnapply(const float* __restrict__ e_ln,
    const float* __restrict__ bn_sum, const float* __restrict__ bn_sq,
    const float* __restrict__ bn_g, const float* __restrict__ bn_b,
    float* __restrict__ e_n, float* __restrict__ out_e)
{
    int idx = blockIdx.x * 256 + threadIdx.x;
    int c = idx & 127;
    float m = bn_sum[c] * (1.0f / NE);
    float var = bn_sq[c] * (1.0f / NE) - m * m;
    float x = e_ln[idx];
    float y = (x - m) * rsqrtf(var + EPSV) * bn_g[c] + bn_b[c];
    e_n[idx] = y;
    out_e[idx] = gelu_f(y);
}

// ---------------- Kernel 6: e2v aggregation + gate + LN + residual + gelu
__global__ __launch_bounds__(128) void k_vertex2(
    const float* __restrict__ X, const float* __restrict__ H,
    const float* __restrict__ e_n, const float* __restrict__ Xt,
    const float* __restrict__ Wg, const float* __restrict__ bg,
    const float* __restrict__ ln_g, const float* __restrict__ ln_b,
    float* __restrict__ out_v)
{
    const int VPB = 8;
    const int LCAP = 192;
    __shared__ float Xs[VPB][CIN];
    __shared__ float vf[VPB][COUT];
    __shared__ int lst[LCAP];
    __shared__ int lcount;
    __shared__ float redA[128], redB[128];
    int t = threadIdx.x;
    int v0 = blockIdx.x * VPB;

    for (int v = 0; v < VPB; ++v) {
        Xs[v][t] = X[(v0 + v) * CIN + t];
        if (t == 0) lcount = 0;
        __syncthreads();
        const float* hrow = H + (size_t)(v0 + v) * NE;
        for (int ch = 0; ch < NE / 128; ++ch) {
            float hv = hrow[ch * 128 + t];
            if (hv != 0.0f) {
                int p = atomicAdd(&lcount, 1);
                if (p < LCAP) lst[p] = ch * 128 + t;
            }
        }
        __syncthreads();
        int n = lcount;
        if (n > LCAP) n = LCAP;
        float acc = 0;
        for (int i = 0; i < n; ++i) acc += e_n[lst[i] * COUT + t];
        vf[v][t] = acc;
        __syncthreads();
    }

    // gate = sigmoid([X, vf] @ Wg + bg)
    float accg[VPB];
    float bgc = bg[t];
#pragma unroll
    for (int v = 0; v < VPB; ++v) accg[v] = bgc;
    for (int k = 0; k < CIN; ++k) {
        float w = Wg[k * COUT + t];
#pragma unroll
        for (int v = 0; v < VPB; ++v) accg[v] = fmaf(Xs[v][k], w, accg[v]);
    }
    for (int k = 0; k < COUT; ++k) {
        float w = Wg[(CIN + k) * COUT + t];
#pragma unroll
        for (int v = 0; v < VPB; ++v) accg[v] = fmaf(vf[v][k], w, accg[v]);
    }

    for (int v = 0; v < VPB; ++v) {
        float gate = sigmoid_f(accg[v]);
        float xt = Xt[(v0 + v) * COUT + t];
        float x = gate * vf[v][t] + (1.0f - gate) * xt;
        redA[t] = x;
        redB[t] = x * x;
        __syncthreads();
        for (int s = 64; s >= 1; s >>= 1) {
            if (t < s) { redA[t] += redA[t + s]; redB[t] += redB[t + s]; }
            __syncthreads();
        }
        float m = redA[0] * (1.0f / COUT);
        float var = redB[0] * (1.0f / COUT) - m * m;
        float y = (x - m) * rsqrtf(var + EPSV) * ln_g[t] + ln_b[t];
        y = y + Xs[v][t];
        out_v[(v0 + v) * COUT + t] = gelu_f(y);
        __syncthreads();
    }
}

extern "C" void kernel_launch(void* const* d_in, const int* in_sizes, int n_in,
                              void* d_out, int out_size, void* d_ws, size_t ws_size,
                              hipStream_t stream) {
    const float* X    = (const float*)d_in[0];
    const float* H    = (const float*)d_in[1];
    const float* edge_features = (const float*)d_in[2];
    const float* Wv   = (const float*)d_in[3];
    const float* bv   = (const float*)d_in[4];
    const float* We   = (const float*)d_in[5];
    const float* be   = (const float*)d_in[6];
    const float* vW1  = (const float*)d_in[7];
    const float* vb1  = (const float*)d_in[8];
    const float* vW2  = (const float*)d_in[9];
    const float* vb2  = (const float*)d_in[10];
    const float* eW1  = (const float*)d_in[11];
    const float* eb1  = (const float*)d_in[12];
    const float* eW2  = (const float*)d_in[13];
    const float* eb2  = (const float*)d_in[14];
    const float* Wc   = (const float*)d_in[15];
    const float* bc   = (const float*)d_in[16];
    const float* ln_e_g = (const float*)d_in[17];
    const float* ln_e_b = (const float*)d_in[18];
    const float* ln_v_g = (const float*)d_in[19];
    const float* ln_v_b = (const float*)d_in[20];
    const float* bn_g = (const float*)d_in[21];
    const float* bn_b = (const float*)d_in[22];
    const float* Wg   = (const float*)d_in[23];
    const float* bg   = (const float*)d_in[24];

    float* out_v  = (float*)d_out;            // V*COUT
    float* out_e  = out_v + NV * COUT;        // E*COUT
    float* out_att = out_e + NE * COUT;       // E

    char* w = (char*)d_ws;
    float* Xt     = (float*)w; w += (size_t)NV * COUT * 4;
    float* attn4  = (float*)w; w += (size_t)NV * NH * 4;
    float* e_ln   = (float*)w; w += (size_t)NE * COUT * 4;
    float* e_n    = (float*)w; w += (size_t)NE * COUT * 4;
    float* bn_sum = (float*)w; w += COUT * 4;
    float* bn_sq  = (float*)w; w += COUT * 4;
    int*   cnt    = (int*)w;   w += NE * 4;
    int*   elist  = (int*)w;   w += (size_t)NE * MAXDEG * 4;

    // zero bn_sum, bn_sq, cnt (contiguous)
    hipMemsetAsync(bn_sum, 0, (2 * COUT + NE) * sizeof(float), stream);

    k_vertex1<<<NV / 8, 128, 0, stream>>>(X, Wv, bv, vW1, vb1, vW2, vb2, Xt, attn4);
    k_build<<<(NV * NE) / (256 * 4), 256, 0, stream>>>(H, cnt, elist);
    k_edge<<<NE / 2, 256, 0, stream>>>(Xt, attn4, cnt, elist, edge_features,
                                       Wc, bc, We, be, eW1, eb1, eW2, eb2,
                                       ln_e_g, ln_e_b, e_ln, out_att);
    k_bnstats<<<NE / 64, 128, 0, stream>>>(e_ln, bn_sum, bn_sq);
    k_bnapply<<<(NE * COUT) / 256, 256, 0, stream>>>(e_ln, bn_sum, bn_sq, bn_g, bn_b, e_n, out_e);
    k_vertex2<<<NV / 8, 128, 0, stream>>>(X, H, e_n, Xt, Wg, bg, ln_v_g, ln_v_b, out_v);
}

// Round 3
// 393.097 us; speedup vs baseline: 1.0244x; 1.0244x over previous
//
#include <hip/hip_runtime.h>
#include <hip/hip_bf16.h>
#include <math.h>

#define NV 8192
#define NE 2048
#define CIN 128
#define COUT 128
#define NH 4
#define HID 32
#define MAXDEG 256
#define VCAP 96
#define EPSV 1e-5f

__device__ __forceinline__ float gelu_f(float x) {
    return 0.5f * x * (1.0f + erff(x * 0.70710678118654752f));
}
__device__ __forceinline__ float sigmoid_f(float x) {
    return 1.0f / (1.0f + expf(-x));
}

// ---------------- Kernel 1: Xt = X@Wv+bv ; attn[h,v] = sigmoid(gelu(X@vW1+vb1)@vW2+vb2)
__global__ __launch_bounds__(128) void k_vertex1(
    const float* __restrict__ X, const float* __restrict__ Wv, const float* __restrict__ bv,
    const float* __restrict__ vW1, const float* __restrict__ vb1,
    const float* __restrict__ vW2, const float* __restrict__ vb2,
    float* __restrict__ Xt, float* __restrict__ attn4)
{
    const int VPB = 8;
    __shared__ float Xs[VPB][CIN];
    int t = threadIdx.x;
    int v0 = blockIdx.x * VPB;
    for (int v = 0; v < VPB; ++v) Xs[v][t] = X[(v0 + v) * CIN + t];
    __syncthreads();

    float acc[VPB];
    float bvc = bv[t];
#pragma unroll
    for (int v = 0; v < VPB; ++v) acc[v] = bvc;
    for (int k = 0; k < CIN; ++k) {
        float w = Wv[k * COUT + t];
#pragma unroll
        for (int v = 0; v < VPB; ++v) acc[v] = fmaf(Xs[v][k], w, acc[v]);
    }
    for (int v = 0; v < VPB; ++v) Xt[(v0 + v) * COUT + t] = acc[v];

    // per-head MLP: thread t -> (head h, hidden j)
    int h = t >> 5, j = t & 31;
    float hb = vb1[h * HID + j];
#pragma unroll
    for (int v = 0; v < VPB; ++v) acc[v] = hb;
    for (int k = 0; k < CIN; ++k) {
        float w = vW1[(h * CIN + k) * HID + j];
#pragma unroll
        for (int v = 0; v < VPB; ++v) acc[v] = fmaf(Xs[v][k], w, acc[v]);
    }
    float w2 = vW2[h * HID + j];
    float b2 = vb2[h];
    for (int v = 0; v < VPB; ++v) {
        float val = gelu_f(acc[v]) * w2;
#pragma unroll
        for (int m = 16; m >= 1; m >>= 1) val += __shfl_xor(val, m, 64);
        if (j == 0) attn4[(v0 + v) * NH + h] = sigmoid_f(val + b2);
    }
}

// ---------------- Kernel 2: one pass over H builds edge lists (atomic) + vertex lists (ballot)
__global__ __launch_bounds__(256) void k_build(
    const float* __restrict__ H, int* __restrict__ cnt, int* __restrict__ elist,
    int* __restrict__ vdeg, int* __restrict__ vlist)
{
    int w = threadIdx.x >> 6;
    int lane = threadIdx.x & 63;
    int v = blockIdx.x * 4 + w;
    const float* row = H + (size_t)v * NE;
    unsigned long long lt = (1ull << lane) - 1ull;
    int base = 0;
    int* vl = vlist + (size_t)v * VCAP;
#pragma unroll
    for (int it = 0; it < NE / 256; ++it) {
        float4 h4 = *(const float4*)(row + it * 256 + lane * 4);
        float hv[4] = {h4.x, h4.y, h4.z, h4.w};
#pragma unroll
        for (int j = 0; j < 4; ++j) {
            bool nz = hv[j] != 0.0f;
            unsigned long long m = __ballot(nz);
            if (nz) {
                int e = it * 256 + lane * 4 + j;
                int pos = base + __popcll(m & lt);
                if (pos < VCAP) vl[pos] = e;
                int p = atomicAdd(&cnt[e], 1);
                if (p < MAXDEG) elist[e * MAXDEG + p] = v;
            }
            base += __popcll(m);
        }
    }
    if (lane == 0) vdeg[v] = base;
}

// ---------------- Kernel 3: per-edge aggregation + combine + gating + LN (pre-BN)
__global__ __launch_bounds__(256) void k_edge(
    const float* __restrict__ Xt, const float* __restrict__ attn4,
    const int* __restrict__ cnt, const int* __restrict__ elist,
    const float* __restrict__ edge_features,
    const float* __restrict__ Wc, const float* __restrict__ bc,
    const float* __restrict__ We, const float* __restrict__ be,
    const float* __restrict__ eW1, const float* __restrict__ eb1,
    const float* __restrict__ eW2, const float* __restrict__ eb2,
    const float* __restrict__ ln_g, const float* __restrict__ ln_b,
    float* __restrict__ e_ln, float* __restrict__ out_att)
{
    __shared__ int lst[MAXDEG];
    __shared__ float part[2][5][COUT];
    __shared__ float ecat[NH * COUT];
    __shared__ float efpart[2][COUT];
    __shared__ float efr[COUT];
    __shared__ float efs[COUT];
    __shared__ float teL[COUT];
    __shared__ float ews_l;
    __shared__ float red[2][2];
    int t = threadIdx.x;
    int g = t >> 7, c = t & 127;
    int e = blockIdx.x;

    int n0 = cnt[e];
    float inv = 1.0f / fmaxf((float)n0, 1.0f);
    int n = n0 < MAXDEG ? n0 : MAXDEG;
    if (t < 128) efr[t] = edge_features[e * COUT + t];
    if (t < n) lst[t] = elist[e * MAXDEG + t];
    __syncthreads();

    float a0 = 0, a1 = 0, a2 = 0, a3 = 0, as = 0;
    for (int i = g; i < n; i += 2) {
        int v = lst[i];
        float x = Xt[v * COUT + c];
        float4 a = *(const float4*)(attn4 + v * NH);
        a0 = fmaf(x, a.x, a0);
        a1 = fmaf(x, a.y, a1);
        a2 = fmaf(x, a.z, a2);
        a3 = fmaf(x, a.w, a3);
        as += a.w;
    }
    part[g][0][c] = a0; part[g][1][c] = a1; part[g][2][c] = a2; part[g][3][c] = a3;
    part[g][4][c] = as;
    __syncthreads();

    if (t < 128) {
#pragma unroll
        for (int h = 0; h < 4; ++h) ecat[h * COUT + t] = (part[0][h][t] + part[1][h][t]) * inv;
    }
    if (t == 0) out_att[e] = (part[0][4][0] + part[1][4][0]) * inv;
    __syncthreads();

    // ef = ecat @ Wc + bc, split-K across the two groups
    float acc = 0;
    int k0 = g * 256;
    for (int k = 0; k < 256; ++k) acc = fmaf(ecat[k0 + k], Wc[(k0 + k) * COUT + c], acc);
    efpart[g][c] = acc;
    __syncthreads();
    if (t < 128) efs[t] = efpart[0][t] + efpart[1][t] + bc[t];
    __syncthreads();

    // concurrently: lanes 0..31 do score MLP; threads 128..255 do te GEMM
    if (t < 32) {
        float hj = eb1[t];
        for (int k = 0; k < COUT; ++k) hj = fmaf(efs[k], eW1[k * HID + t], hj);
        float val = gelu_f(hj) * eW2[t];
#pragma unroll
        for (int m = 16; m >= 1; m >>= 1) val += __shfl_xor(val, m, 64);
        if (t == 0) ews_l = sigmoid_f(val + eb2[0]);
    } else if (t >= 128) {
        float te = be[c];
        for (int k = 0; k < COUT; ++k) te = fmaf(efr[k], We[k * COUT + c], te);
        teL[c] = te;
    }
    __syncthreads();

    float x = 0;
    if (t < 128) {
        float ew = ews_l;
        x = efs[t] * ew + teL[t] * (1.0f - ew);
        float s = x, q = x * x;
#pragma unroll
        for (int m = 32; m >= 1; m >>= 1) { s += __shfl_xor(s, m, 64); q += __shfl_xor(q, m, 64); }
        if ((t & 63) == 0) { red[t >> 6][0] = s; red[t >> 6][1] = q; }
    }
    __syncthreads();
    if (t < 128) {
        float S = red[0][0] + red[1][0];
        float Q = red[0][1] + red[1][1];
        float m = S * (1.0f / COUT);
        float var = Q * (1.0f / COUT) - m * m;
        float y = (x - m) * rsqrtf(var + EPSV) * ln_g[t] + ln_b[t];
        e_ln[e * COUT + t] = y;
    }
}

// ---------------- Kernel 4: BN stats over edges (per channel)
__global__ __launch_bounds__(128) void k_bnstats(const float* __restrict__ e_ln,
    float* __restrict__ bn_sum, float* __restrict__ bn_sq)
{
    int c = threadIdx.x;
    int e0 = blockIdx.x * 64;
    float s = 0, q = 0;
    for (int i = 0; i < 64; ++i) {
        float x = e_ln[(e0 + i) * COUT + c];
        s += x;
        q += x * x;
    }
    atomicAdd(&bn_sum[c], s);
    atomicAdd(&bn_sq[c], q);
}

// ---------------- Kernel 5: BN apply + e_feat output (gelu)
__global__ __launch_bounds__(256) void k_bnapply(const float* __restrict__ e_ln,
    const float* __restrict__ bn_sum, const float* __restrict__ bn_sq,
    const float* __restrict__ bn_g, const float* __restrict__ bn_b,
    float* __restrict__ e_n, float* __restrict__ out_e)
{
    int idx = blockIdx.x * 256 + threadIdx.x;
    int c = idx & 127;
    float m = bn_sum[c] * (1.0f / NE);
    float var = bn_sq[c] * (1.0f / NE) - m * m;
    float x = e_ln[idx];
    float y = (x - m) * rsqrtf(var + EPSV) * bn_g[c] + bn_b[c];
    e_n[idx] = y;
    out_e[idx] = gelu_f(y);
}

// ---------------- Kernel 6: e2v via prebuilt vertex lists + gate + LN + residual + gelu
__global__ __launch_bounds__(256) void k_vertex2(
    const float* __restrict__ X, const int* __restrict__ vdeg, const int* __restrict__ vlist,
    const float* __restrict__ e_n, const float* __restrict__ Xt,
    const float* __restrict__ Wg, const float* __restrict__ bg,
    const float* __restrict__ ln_g, const float* __restrict__ ln_b,
    float* __restrict__ out_v)
{
    const int VPB = 8;
    __shared__ float Xs[VPB][CIN];
    __shared__ float vf[VPB][COUT];
    __shared__ int lst[VPB][VCAP];
    __shared__ int degs[VPB];
    __shared__ float red[4][2];
    int t = threadIdx.x;
    int g = t >> 7, c = t & 127;
    int v0 = blockIdx.x * VPB;

#pragma unroll
    for (int r = 0; r < 4; ++r) {
        int vi = g * 4 + r;
        Xs[vi][c] = X[(size_t)(v0 + vi) * CIN + c];
        if (c < VCAP) lst[vi][c] = vlist[(size_t)(v0 + vi) * VCAP + c];
    }
    if (t < VPB) degs[t] = vdeg[v0 + t];
    __syncthreads();

#pragma unroll
    for (int r = 0; r < 4; ++r) {
        int vi = g * 4 + r;
        int n = degs[vi];
        if (n > VCAP) n = VCAP;
        float acc = 0;
        for (int i = 0; i < n; ++i) acc += e_n[lst[vi][i] * COUT + c];
        vf[vi][c] = acc;
    }
    __syncthreads();

    // gate = sigmoid([X, vf] @ Wg + bg)
    float accg[4];
    float bgc = bg[c];
#pragma unroll
    for (int r = 0; r < 4; ++r) accg[r] = bgc;
    for (int k = 0; k < CIN; ++k) {
        float w = Wg[k * COUT + c];
#pragma unroll
        for (int r = 0; r < 4; ++r) accg[r] = fmaf(Xs[g * 4 + r][k], w, accg[r]);
    }
    for (int k = 0; k < COUT; ++k) {
        float w = Wg[(CIN + k) * COUT + c];
#pragma unroll
        for (int r = 0; r < 4; ++r) accg[r] = fmaf(vf[g * 4 + r][k], w, accg[r]);
    }

    int wv = t >> 6;
#pragma unroll
    for (int r = 0; r < 4; ++r) {
        int vi = g * 4 + r;
        float gate = sigmoid_f(accg[r]);
        float xt = Xt[(size_t)(v0 + vi) * COUT + c];
        float x = gate * vf[vi][c] + (1.0f - gate) * xt;
        float s = x, q = x * x;
#pragma unroll
        for (int m = 32; m >= 1; m >>= 1) { s += __shfl_xor(s, m, 64); q += __shfl_xor(q, m, 64); }
        if ((t & 63) == 0) { red[wv][0] = s; red[wv][1] = q; }
        __syncthreads();
        float S = red[g * 2][0] + red[g * 2 + 1][0];
        float Q = red[g * 2][1] + red[g * 2 + 1][1];
        float m_ = S * (1.0f / COUT);
        float var = Q * (1.0f / COUT) - m_ * m_;
        float y = (x - m_) * rsqrtf(var + EPSV) * ln_g[c] + ln_b[c];
        y = y + Xs[vi][c];
        out_v[(size_t)(v0 + vi) * COUT + c] = gelu_f(y);
        __syncthreads();
    }
}

extern "C" void kernel_launch(void* const* d_in, const int* in_sizes, int n_in,
                              void* d_out, int out_size, void* d_ws, size_t ws_size,
                              hipStream_t stream) {
    const float* X    = (const float*)d_in[0];
    const float* H    = (const float*)d_in[1];
    const float* edge_features = (const float*)d_in[2];
    const float* Wv   = (const float*)d_in[3];
    const float* bv   = (const float*)d_in[4];
    const float* We   = (const float*)d_in[5];
    const float* be   = (const float*)d_in[6];
    const float* vW1  = (const float*)d_in[7];
    const float* vb1  = (const float*)d_in[8];
    const float* vW2  = (const float*)d_in[9];
    const float* vb2  = (const float*)d_in[10];
    const float* eW1  = (const float*)d_in[11];
    const float* eb1  = (const float*)d_in[12];
    const float* eW2  = (const float*)d_in[13];
    const float* eb2  = (const float*)d_in[14];
    const float* Wc   = (const float*)d_in[15];
    const float* bc   = (const float*)d_in[16];
    const float* ln_e_g = (const float*)d_in[17];
    const float* ln_e_b = (const float*)d_in[18];
    const float* ln_v_g = (const float*)d_in[19];
    const float* ln_v_b = (const float*)d_in[20];
    const float* bn_g = (const float*)d_in[21];
    const float* bn_b = (const float*)d_in[22];
    const float* Wg   = (const float*)d_in[23];
    const float* bg   = (const float*)d_in[24];

    float* out_v  = (float*)d_out;            // V*COUT
    float* out_e  = out_v + NV * COUT;        // E*COUT
    float* out_att = out_e + NE * COUT;       // E

    char* w = (char*)d_ws;
    float* Xt     = (float*)w; w += (size_t)NV * COUT * 4;
    float* attn4  = (float*)w; w += (size_t)NV * NH * 4;
    float* e_ln   = (float*)w; w += (size_t)NE * COUT * 4;
    float* e_n    = (float*)w; w += (size_t)NE * COUT * 4;
    float* bn_sum = (float*)w; w += COUT * 4;
    float* bn_sq  = (float*)w; w += COUT * 4;
    int*   cnt    = (int*)w;   w += NE * 4;
    int*   elist  = (int*)w;   w += (size_t)NE * MAXDEG * 4;
    int*   vdeg   = (int*)w;   w += (size_t)NV * 4;
    int*   vlist  = (int*)w;   w += (size_t)NV * VCAP * 4;

    // zero bn_sum, bn_sq, cnt (contiguous)
    hipMemsetAsync(bn_sum, 0, (2 * COUT + NE) * sizeof(float), stream);

    k_vertex1<<<NV / 8, 128, 0, stream>>>(X, Wv, bv, vW1, vb1, vW2, vb2, Xt, attn4);
    k_build<<<NV / 4, 256, 0, stream>>>(H, cnt, elist, vdeg, vlist);
    k_edge<<<NE, 256, 0, stream>>>(Xt, attn4, cnt, elist, edge_features,
                                   Wc, bc, We, be, eW1, eb1, eW2, eb2,
                                   ln_e_g, ln_e_b, e_ln, out_att);
    k_bnstats<<<NE / 64, 128, 0, stream>>>(e_ln, bn_sum, bn_sq);
    k_bnapply<<<(NE * COUT) / 256, 256, 0, stream>>>(e_ln, bn_sum, bn_sq, bn_g, bn_b, e_n, out_e);
    k_vertex2<<<NV / 8, 256, 0, stream>>>(X, vdeg, vlist, e_n, Xt, Wg, bg, ln_v_g, ln_v_b, out_v);
}

// Round 4
// 348.000 us; speedup vs baseline: 1.1572x; 1.1296x over previous
//
#include <hip/hip_runtime.h>
#include <hip/hip_bf16.h>
#include <math.h>

#define NV 8192
#define NE 2048
#define CIN 128
#define COUT 128
#define NH 4
#define HID 32
#define LCAP 320
#define VCAP 96
#define NWORDS (NE / 64)
#define EPSV 1e-5f

__device__ __forceinline__ float gelu_f(float x) {
    return 0.5f * x * (1.0f + erff(x * 0.70710678118654752f));
}
__device__ __forceinline__ float sigmoid_f(float x) {
    return 1.0f / (1.0f + expf(-x));
}

// ---------------- Kernel 1: Xt = X@Wv+bv ; attn[h,v] = sigmoid(gelu(X@vW1+vb1)@vW2+vb2)
__global__ __launch_bounds__(128) void k_vertex1(
    const float* __restrict__ X, const float* __restrict__ Wv, const float* __restrict__ bv,
    const float* __restrict__ vW1, const float* __restrict__ vb1,
    const float* __restrict__ vW2, const float* __restrict__ vb2,
    float* __restrict__ Xt, float* __restrict__ attn4)
{
    const int VPB = 8;
    __shared__ float Xs[VPB][CIN];
    int t = threadIdx.x;
    int v0 = blockIdx.x * VPB;
    for (int v = 0; v < VPB; ++v) Xs[v][t] = X[(v0 + v) * CIN + t];
    __syncthreads();

    float acc[VPB];
    float bvc = bv[t];
#pragma unroll
    for (int v = 0; v < VPB; ++v) acc[v] = bvc;
    for (int k = 0; k < CIN; ++k) {
        float w = Wv[k * COUT + t];
#pragma unroll
        for (int v = 0; v < VPB; ++v) acc[v] = fmaf(Xs[v][k], w, acc[v]);
    }
    for (int v = 0; v < VPB; ++v) Xt[(v0 + v) * COUT + t] = acc[v];

    int h = t >> 5, j = t & 31;
    float hb = vb1[h * HID + j];
#pragma unroll
    for (int v = 0; v < VPB; ++v) acc[v] = hb;
    for (int k = 0; k < CIN; ++k) {
        float w = vW1[(h * CIN + k) * HID + j];
#pragma unroll
        for (int v = 0; v < VPB; ++v) acc[v] = fmaf(Xs[v][k], w, acc[v]);
    }
    float w2 = vW2[h * HID + j];
    float b2 = vb2[h];
    for (int v = 0; v < VPB; ++v) {
        float val = gelu_f(acc[v]) * w2;
#pragma unroll
        for (int m = 16; m >= 1; m >>= 1) val += __shfl_xor(val, m, 64);
        if (j == 0) attn4[(v0 + v) * NH + h] = sigmoid_f(val + b2);
    }
}

// ---------------- Kernel 2: streaming pass over H -> column bitmap + per-vertex edge lists
// No atomics anywhere. Wave per row, scalar coalesced loads, one ballot per 64 edges.
__global__ __launch_bounds__(256) void k_build(
    const float* __restrict__ H, unsigned long long* __restrict__ Hbits,
    int* __restrict__ vdeg, int* __restrict__ vlist)
{
    int w = threadIdx.x >> 6;
    int lane = threadIdx.x & 63;
    int v = blockIdx.x * 4 + w;
    const float* row = H + (size_t)v * NE;
    unsigned long long lt = (1ull << lane) - 1ull;
    int base = 0;
    int* vl = vlist + (size_t)v * VCAP;
#pragma unroll 8
    for (int it = 0; it < NWORDS; ++it) {
        float hv = row[it * 64 + lane];
        bool nz = hv != 0.0f;
        unsigned long long m = __ballot(nz);
        if (lane == 0) Hbits[(size_t)v * NWORDS + it] = m;
        if (nz) {
            int pos = base + __popcll(m & lt);
            if (pos < VCAP) vl[pos] = it * 64 + lane;
        }
        base += __popcll(m);
    }
    if (lane == 0) vdeg[v] = base;
}

// ---------------- Kernel 3: per-edge: bitmap->list (scan compaction), aggregation,
// combine (split-K Wc), score MLP, te GEMM, blend, LN. Block = 512 threads, 1 edge.
__global__ __launch_bounds__(512) void k_edge(
    const float* __restrict__ Xt, const float* __restrict__ attn4,
    const unsigned long long* __restrict__ Hbits,
    const float* __restrict__ edge_features,
    const float* __restrict__ Wc, const float* __restrict__ bc,
    const float* __restrict__ We, const float* __restrict__ be,
    const float* __restrict__ eW1, const float* __restrict__ eb1,
    const float* __restrict__ eW2, const float* __restrict__ eb2,
    const float* __restrict__ ln_g, const float* __restrict__ ln_b,
    float* __restrict__ e_ln, float* __restrict__ out_att)
{
    __shared__ int lst[LCAP];
    __shared__ int wsum[8];
    __shared__ int ntot_s;
    __shared__ float part[4][5][COUT];
    __shared__ float ecat[NH * COUT];
    __shared__ float efpart[4][COUT];
    __shared__ float efr[COUT];
    __shared__ float efs[COUT];
    __shared__ float teL[COUT];
    __shared__ float ews_l;
    __shared__ float red[2][2];

    int t = threadIdx.x;
    int lane = t & 63, wid = t >> 6;
    int g = t >> 7, c = t & 127;
    int e = blockIdx.x;
    int we = e >> 6, bit = e & 63;

    if (t < 128) efr[t] = edge_features[e * COUT + t];

    // ---- build member list from bitmap (16 vertices per thread) ----
    unsigned int myMask = 0;
    int vb = t * 16;
#pragma unroll
    for (int i = 0; i < 16; ++i) {
        unsigned long long wd = Hbits[(size_t)(vb + i) * NWORDS + we];
        myMask |= (unsigned int)((wd >> bit) & 1ull) << i;
    }
    int cntT = __popc(myMask);
    int inc = cntT;
#pragma unroll
    for (int s = 1; s < 64; s <<= 1) {
        int y = __shfl_up(inc, s, 64);
        if (lane >= s) inc += y;
    }
    if (lane == 63) wsum[wid] = inc;
    __syncthreads();
    if (t == 0) {
        int b = 0;
#pragma unroll
        for (int i = 0; i < 8; ++i) { int x = wsum[i]; wsum[i] = b; b += x; }
        ntot_s = b;
    }
    __syncthreads();
    int off = wsum[wid] + inc - cntT;
    unsigned int mm = myMask;
    while (mm) {
        int i = __ffs(mm) - 1;
        mm &= mm - 1;
        if (off < LCAP) lst[off] = vb + i;
        ++off;
    }
    __syncthreads();

    int n0 = ntot_s;
    float inv = 1.0f / fmaxf((float)n0, 1.0f);
    int n = n0 < LCAP ? n0 : LCAP;

    // ---- aggregation: 4 groups stride the member list ----
    float a0 = 0, a1 = 0, a2 = 0, a3 = 0, as = 0;
    for (int i = g; i < n; i += 4) {
        int v = lst[i];
        float x = Xt[v * COUT + c];
        float4 a = *(const float4*)(attn4 + v * NH);
        a0 = fmaf(x, a.x, a0);
        a1 = fmaf(x, a.y, a1);
        a2 = fmaf(x, a.z, a2);
        a3 = fmaf(x, a.w, a3);
        as += a.w;
    }
    part[g][0][c] = a0; part[g][1][c] = a1; part[g][2][c] = a2; part[g][3][c] = a3;
    part[g][4][c] = as;
    __syncthreads();

    // ecat[k], k = h*COUT + c' ; built by all 512 threads
    {
        int h = t >> 7, cc = t & 127;
        ecat[t] = (part[0][h][cc] + part[1][h][cc] + part[2][h][cc] + part[3][h][cc]) * inv;
    }
    if (t == 0) out_att[e] = (part[0][4][0] + part[1][4][0] + part[2][4][0] + part[3][4][0]) * inv;
    __syncthreads();

    // ef = ecat @ Wc + bc, split-K over 4 groups (K=128 each)
    {
        float acc = 0;
        int k0 = g * 128;
        for (int k = 0; k < 128; ++k) acc = fmaf(ecat[k0 + k], Wc[(k0 + k) * COUT + c], acc);
        efpart[g][c] = acc;
    }
    __syncthreads();
    if (t < 128) efs[t] = efpart[0][t] + efpart[1][t] + efpart[2][t] + efpart[3][t] + bc[t];
    __syncthreads();

    // concurrently: lanes 0..31 score MLP; threads 128..255 te GEMM
    if (t < 32) {
        float hj = eb1[t];
        for (int k = 0; k < COUT; ++k) hj = fmaf(efs[k], eW1[k * HID + t], hj);
        float val = gelu_f(hj) * eW2[t];
#pragma unroll
        for (int m = 16; m >= 1; m >>= 1) val += __shfl_xor(val, m, 64);
        if (t == 0) ews_l = sigmoid_f(val + eb2[0]);
    } else if (t >= 128 && t < 256) {
        float te = be[c];
        for (int k = 0; k < COUT; ++k) te = fmaf(efr[k], We[k * COUT + c], te);
        teL[c] = te;
    }
    __syncthreads();

    if (t < 128) {
        float ew = ews_l;
        float x = efs[t] * ew + teL[t] * (1.0f - ew);
        float s = x, q = x * x;
#pragma unroll
        for (int m = 32; m >= 1; m >>= 1) { s += __shfl_xor(s, m, 64); q += __shfl_xor(q, m, 64); }
        if ((t & 63) == 0) { red[t >> 6][0] = s; red[t >> 6][1] = q; }
        __syncthreads();
        float S = red[0][0] + red[1][0];
        float Q = red[0][1] + red[1][1];
        float m = S * (1.0f / COUT);
        float var = Q * (1.0f / COUT) - m * m;
        float y = (x - m) * rsqrtf(var + EPSV) * ln_g[t] + ln_b[t];
        e_ln[e * COUT + t] = y;
    } else {
        __syncthreads();
    }
}

// ---------------- Kernel 4: BN stats over edges (per channel)
__global__ __launch_bounds__(128) void k_bnstats(const float* __restrict__ e_ln,
    float* __restrict__ bn_sum, float* __restrict__ bn_sq)
{
    int c = threadIdx.x;
    int e0 = blockIdx.x * 16;
    float s = 0, q = 0;
    for (int i = 0; i < 16; ++i) {
        float x = e_ln[(e0 + i) * COUT + c];
        s += x;
        q += x * x;
    }
    atomicAdd(&bn_sum[c], s);
    atomicAdd(&bn_sq[c], q);
}

// ---------------- Kernel 5: BN apply + e_feat output (gelu)
__global__ __launch_bounds__(256) void k_bnapply(const float* __restrict__ e_ln,
    const float* __restrict__ bn_sum, const float* __restrict__ bn_sq,
    const float* __restrict__ bn_g, const float* __restrict__ bn_b,
    float* __restrict__ e_n, float* __restrict__ out_e)
{
    int idx = blockIdx.x * 256 + threadIdx.x;
    int c = idx & 127;
    float m = bn_sum[c] * (1.0f / NE);
    float var = bn_sq[c] * (1.0f / NE) - m * m;
    float x = e_ln[idx];
    float y = (x - m) * rsqrtf(var + EPSV) * bn_g[c] + bn_b[c];
    e_n[idx] = y;
    out_e[idx] = gelu_f(y);
}

// ---------------- Kernel 6: e2v via prebuilt vertex lists + gate + LN + residual + gelu
// Block = 512 threads = 4 groups x 128; each group handles ONE vertex.
__global__ __launch_bounds__(512) void k_vertex2(
    const float* __restrict__ X, const int* __restrict__ vdeg, const int* __restrict__ vlist,
    const float* __restrict__ e_n, const float* __restrict__ Xt,
    const float* __restrict__ Wg, const float* __restrict__ bg,
    const float* __restrict__ ln_g, const float* __restrict__ ln_b,
    float* __restrict__ out_v)
{
    __shared__ float Xs[4][CIN];
    __shared__ float vf[4][COUT];
    __shared__ int lst[4][VCAP];
    __shared__ int degs[4];
    __shared__ float red[8][2];
    int t = threadIdx.x;
    int g = t >> 7, c = t & 127;
    int wid = t >> 6;
    int v0 = blockIdx.x * 4;
    int v = v0 + g;

    Xs[g][c] = X[(size_t)v * CIN + c];
    if (c < VCAP) lst[g][c] = vlist[(size_t)v * VCAP + c];
    if (t < 4) degs[t] = vdeg[v0 + t];
    __syncthreads();

    int n = degs[g];
    if (n > VCAP) n = VCAP;
    float acc = 0;
    for (int i = 0; i < n; ++i) acc += e_n[lst[g][i] * COUT + c];
    vf[g][c] = acc;
    __syncthreads();

    float ag = bg[c];
    for (int k = 0; k < CIN; ++k) ag = fmaf(Xs[g][k], Wg[k * COUT + c], ag);
    for (int k = 0; k < COUT; ++k) ag = fmaf(vf[g][k], Wg[(CIN + k) * COUT + c], ag);

    float gate = sigmoid_f(ag);
    float xt = Xt[(size_t)v * COUT + c];
    float x = gate * vf[g][c] + (1.0f - gate) * xt;
    float s = x, q = x * x;
#pragma unroll
    for (int m = 32; m >= 1; m >>= 1) { s += __shfl_xor(s, m, 64); q += __shfl_xor(q, m, 64); }
    if ((t & 63) == 0) { red[wid][0] = s; red[wid][1] = q; }
    __syncthreads();
    float S = red[g * 2][0] + red[g * 2 + 1][0];
    float Q = red[g * 2][1] + red[g * 2 + 1][1];
    float m_ = S * (1.0f / COUT);
    float var = Q * (1.0f / COUT) - m_ * m_;
    float y = (x - m_) * rsqrtf(var + EPSV) * ln_g[c] + ln_b[c];
    y = y + Xs[g][c];
    out_v[(size_t)v * COUT + c] = gelu_f(y);
}

extern "C" void kernel_launch(void* const* d_in, const int* in_sizes, int n_in,
                              void* d_out, int out_size, void* d_ws, size_t ws_size,
                              hipStream_t stream) {
    const float* X    = (const float*)d_in[0];
    const float* H    = (const float*)d_in[1];
    const float* edge_features = (const float*)d_in[2];
    const float* Wv   = (const float*)d_in[3];
    const float* bv   = (const float*)d_in[4];
    const float* We   = (const float*)d_in[5];
    const float* be   = (const float*)d_in[6];
    const float* vW1  = (const float*)d_in[7];
    const float* vb1  = (const float*)d_in[8];
    const float* vW2  = (const float*)d_in[9];
    const float* vb2  = (const float*)d_in[10];
    const float* eW1  = (const float*)d_in[11];
    const float* eb1  = (const float*)d_in[12];
    const float* eW2  = (const float*)d_in[13];
    const float* eb2  = (const float*)d_in[14];
    const float* Wc   = (const float*)d_in[15];
    const float* bc   = (const float*)d_in[16];
    const float* ln_e_g = (const float*)d_in[17];
    const float* ln_e_b = (const float*)d_in[18];
    const float* ln_v_g = (const float*)d_in[19];
    const float* ln_v_b = (const float*)d_in[20];
    const float* bn_g = (const float*)d_in[21];
    const float* bn_b = (const float*)d_in[22];
    const float* Wg   = (const float*)d_in[23];
    const float* bg   = (const float*)d_in[24];

    float* out_v  = (float*)d_out;            // V*COUT
    float* out_e  = out_v + NV * COUT;        // E*COUT
    float* out_att = out_e + NE * COUT;       // E

    char* w = (char*)d_ws;
    float* Xt     = (float*)w; w += (size_t)NV * COUT * 4;
    float* attn4  = (float*)w; w += (size_t)NV * NH * 4;
    float* e_ln   = (float*)w; w += (size_t)NE * COUT * 4;
    float* e_n    = (float*)w; w += (size_t)NE * COUT * 4;
    float* bn_sum = (float*)w; w += COUT * 4;
    float* bn_sq  = (float*)w; w += COUT * 4;
    int*   vdeg   = (int*)w;   w += (size_t)NV * 4;
    int*   vlist  = (int*)w;   w += (size_t)NV * VCAP * 4;
    unsigned long long* Hbits = (unsigned long long*)w; w += (size_t)NV * NWORDS * 8;

    // zero bn_sum, bn_sq
    hipMemsetAsync(bn_sum, 0, 2 * COUT * sizeof(float), stream);

    k_vertex1<<<NV / 8, 128, 0, stream>>>(X, Wv, bv, vW1, vb1, vW2, vb2, Xt, attn4);
    k_build<<<NV / 4, 256, 0, stream>>>(H, Hbits, vdeg, vlist);
    k_edge<<<NE, 512, 0, stream>>>(Xt, attn4, Hbits, edge_features,
                                   Wc, bc, We, be, eW1, eb1, eW2, eb2,
                                   ln_e_g, ln_e_b, e_ln, out_att);
    k_bnstats<<<NE / 16, 128, 0, stream>>>(e_ln, bn_sum, bn_sq);
    k_bnapply<<<(NE * COUT) / 256, 256, 0, stream>>>(e_ln, bn_sum, bn_sq, bn_g, bn_b, e_n, out_e);
    k_vertex2<<<NV / 4, 512, 0, stream>>>(X, vdeg, vlist, e_n, Xt, Wg, bg, ln_v_g, ln_v_b, out_v);
}

// Round 5
// 285.761 us; speedup vs baseline: 1.4092x; 1.2178x over previous
//
#include <hip/hip_runtime.h>
#include <hip/hip_bf16.h>
#include <math.h>

#define NV 8192
#define NE 2048
#define CIN 128
#define COUT 128
#define NH 4
#define HID 32
#define EPB 4
#define LCAP 256
#define VCAP 96
#define NWORDS (NE / 64)
#define TWORDS (NV / 64)
#define EPSV 1e-5f

__device__ __forceinline__ float gelu_f(float x) {
    return 0.5f * x * (1.0f + erff(x * 0.70710678118654752f));
}
__device__ __forceinline__ float sigmoid_f(float x) {
    return 1.0f / (1.0f + expf(-x));
}

// ---------------- Kernel 1: Xt = X@Wv+bv ; attn[h,v] = sigmoid(gelu(X@vW1+vb1)@vW2+vb2)
__global__ __launch_bounds__(128) void k_vertex1(
    const float* __restrict__ X, const float* __restrict__ Wv, const float* __restrict__ bv,
    const float* __restrict__ vW1, const float* __restrict__ vb1,
    const float* __restrict__ vW2, const float* __restrict__ vb2,
    float* __restrict__ Xt, float* __restrict__ attn4)
{
    const int VPB = 8;
    __shared__ float Xs[VPB][CIN];
    int t = threadIdx.x;
    int v0 = blockIdx.x * VPB;
    for (int v = 0; v < VPB; ++v) Xs[v][t] = X[(v0 + v) * CIN + t];
    __syncthreads();

    float acc[VPB];
    float bvc = bv[t];
#pragma unroll
    for (int v = 0; v < VPB; ++v) acc[v] = bvc;
    for (int k = 0; k < CIN; ++k) {
        float w = Wv[k * COUT + t];
#pragma unroll
        for (int v = 0; v < VPB; ++v) acc[v] = fmaf(Xs[v][k], w, acc[v]);
    }
    for (int v = 0; v < VPB; ++v) Xt[(v0 + v) * COUT + t] = acc[v];

    int h = t >> 5, j = t & 31;
    float hb = vb1[h * HID + j];
#pragma unroll
    for (int v = 0; v < VPB; ++v) acc[v] = hb;
    for (int k = 0; k < CIN; ++k) {
        float w = vW1[(h * CIN + k) * HID + j];
#pragma unroll
        for (int v = 0; v < VPB; ++v) acc[v] = fmaf(Xs[v][k], w, acc[v]);
    }
    float w2 = vW2[h * HID + j];
    float b2 = vb2[h];
    for (int v = 0; v < VPB; ++v) {
        float val = gelu_f(acc[v]) * w2;
#pragma unroll
        for (int m = 16; m >= 1; m >>= 1) val += __shfl_xor(val, m, 64);
        if (j == 0) attn4[(v0 + v) * NH + h] = sigmoid_f(val + b2);
    }
}

// ---------------- Kernel 2: streaming pass over H -> row bitmap + per-vertex edge lists
__global__ __launch_bounds__(256) void k_build(
    const float* __restrict__ H, unsigned long long* __restrict__ Hbits,
    int* __restrict__ vdeg, int* __restrict__ vlist)
{
    int w = threadIdx.x >> 6;
    int lane = threadIdx.x & 63;
    int v = blockIdx.x * 4 + w;
    const float* row = H + (size_t)v * NE;
    unsigned long long lt = (1ull << lane) - 1ull;
    int base = 0;
    int* vl = vlist + (size_t)v * VCAP;
#pragma unroll 8
    for (int it = 0; it < NWORDS; ++it) {
        float hv = row[it * 64 + lane];
        bool nz = hv != 0.0f;
        unsigned long long m = __ballot(nz);
        if (lane == 0) Hbits[(size_t)v * NWORDS + it] = m;
        if (nz) {
            int pos = base + __popcll(m & lt);
            if (pos < VCAP) vl[pos] = it * 64 + lane;
        }
        base += __popcll(m);
    }
    if (lane == 0) vdeg[v] = base;
}

// ---------------- Kernel 2b: bit-transpose Hbits[v][e-words] -> HbitsT[e][v-words]
__global__ __launch_bounds__(256) void k_transpose(
    const unsigned long long* __restrict__ Hbits, unsigned long long* __restrict__ HbitsT)
{
    __shared__ unsigned long long rows[64][NWORDS];   // 16 KB
    int t = threadIdx.x;
    int vt = blockIdx.x;              // 0..127 tile of 64 vertices
    for (int i = t; i < 64 * NWORDS; i += 256)
        rows[i >> 5][i & 31] = Hbits[(size_t)vt * 64 * NWORDS + i];
    __syncthreads();
    int wv = t >> 6;
    int lane = t & 63;
    const unsigned long long M[6] = {
        0xFFFFFFFF00000000ULL, 0xFFFF0000FFFF0000ULL, 0xFF00FF00FF00FF00ULL,
        0xF0F0F0F0F0F0F0F0ULL, 0xCCCCCCCCCCCCCCCCULL, 0xAAAAAAAAAAAAAAAAULL };
    const int js[6] = {32, 16, 8, 4, 2, 1};
#pragma unroll
    for (int itb = 0; itb < 8; ++itb) {
        int it = wv * 8 + itb;
        unsigned long long x = rows[lane][it];
#pragma unroll
        for (int s = 0; s < 6; ++s) {
            int j = js[s];
            unsigned long long y = __shfl_xor(x, j, 64);
            unsigned long long Ms = M[s];
            if ((lane & j) == 0) x = (x & ~Ms) | ((y << j) & Ms);
            else                 x = (x & Ms) | ((y >> j) & ~Ms);
        }
        // lane b holds bits over local-vertex l for edge it*64+b
        HbitsT[(size_t)(it * 64 + lane) * TWORDS + vt] = x;
    }
}

// ---------------- Kernel 3: 4 edges/block; group-per-edge membership + aggregation;
// split-K combine with weight loads shared across the 4 edges.
__global__ __launch_bounds__(512) void k_edge(
    const float* __restrict__ Xt, const float* __restrict__ attn4,
    const unsigned long long* __restrict__ HbitsT,
    const float* __restrict__ edge_features,
    const float* __restrict__ Wc, const float* __restrict__ bc,
    const float* __restrict__ We, const float* __restrict__ be,
    const float* __restrict__ eW1, const float* __restrict__ eb1,
    const float* __restrict__ eW2, const float* __restrict__ eb2,
    const float* __restrict__ ln_g, const float* __restrict__ ln_b,
    float* __restrict__ e_ln, float* __restrict__ out_att)
{
    __shared__ int lst[EPB][LCAP];
    __shared__ int wsum[EPB][2];
    __shared__ float ecat[EPB][NH * COUT];
    __shared__ float efpart[4][EPB * COUT];
    __shared__ float tepart[4][EPB * COUT];
    __shared__ float efr_s[EPB][COUT];
    __shared__ float efs[EPB][COUT];
    __shared__ float teL[EPB][COUT];
    __shared__ float ews[EPB];
    __shared__ float red[EPB][2][2];

    int t = threadIdx.x;
    int g = t >> 7;           // group = edge slot
    int c = t & 127;          // channel / word index within group
    int lane = t & 63;
    int gw = (t >> 6) & 1;    // wave within group
    int e0 = blockIdx.x * EPB;
    int e = e0 + g;

    // stage edge_features
    efr_s[g][c] = edge_features[(size_t)e * COUT + c];

    // ---- membership: 1KB coalesced row read + scan compaction ----
    unsigned long long wd = HbitsT[(size_t)e * TWORDS + c];
    int cntT = __popcll(wd);
    int inc = cntT;
#pragma unroll
    for (int s = 1; s < 64; s <<= 1) {
        int y = __shfl_up(inc, s, 64);
        if (lane >= s) inc += y;
    }
    if (lane == 63) wsum[g][gw] = inc;
    __syncthreads();
    int base = (gw ? wsum[g][0] : 0) + inc - cntT;
    int n0 = wsum[g][0] + wsum[g][1];
    int vbase = c * 64;
    unsigned long long mm = wd;
    while (mm) {
        int i = __ffsll(mm) - 1;
        mm &= mm - 1;
        if (base < LCAP) lst[g][base] = vbase + i;
        ++base;
    }
    __syncthreads();

    float inv = 1.0f / fmaxf((float)n0, 1.0f);
    int n = n0 < LCAP ? n0 : LCAP;

    // ---- aggregation: group handles its own edge, channel per thread ----
    float a0 = 0, a1 = 0, a2 = 0, a3 = 0, as = 0;
    for (int i = 0; i < n; ++i) {
        int v = lst[g][i];
        float x = Xt[(size_t)v * COUT + c];
        float4 a = *(const float4*)(attn4 + (size_t)v * NH);
        a0 = fmaf(x, a.x, a0);
        a1 = fmaf(x, a.y, a1);
        a2 = fmaf(x, a.z, a2);
        a3 = fmaf(x, a.w, a3);
        as += a.w;
    }
    ecat[g][0 * COUT + c] = a0 * inv;
    ecat[g][1 * COUT + c] = a1 * inv;
    ecat[g][2 * COUT + c] = a2 * inv;
    ecat[g][3 * COUT + c] = a3 * inv;
    if (c == 0) out_att[e] = as * inv;
    __syncthreads();

    // ---- split-K combine: group g covers K-slice, all 4 edges share each weight load ----
    {
        float accW[EPB] = {0, 0, 0, 0};
        const float* wp = Wc + (size_t)(g * 128) * COUT + c;
        for (int k = 0; k < 128; ++k) {
            float w = wp[k * COUT];
#pragma unroll
            for (int ee = 0; ee < EPB; ++ee)
                accW[ee] = fmaf(ecat[ee][g * 128 + k], w, accW[ee]);
        }
#pragma unroll
        for (int ee = 0; ee < EPB; ++ee) efpart[g][ee * COUT + c] = accW[ee];

        float accT[EPB] = {0, 0, 0, 0};
        const float* wt = We + (size_t)(g * 32) * COUT + c;
        for (int k = 0; k < 32; ++k) {
            float w = wt[k * COUT];
#pragma unroll
            for (int ee = 0; ee < EPB; ++ee)
                accT[ee] = fmaf(efr_s[ee][g * 32 + k], w, accT[ee]);
        }
#pragma unroll
        for (int ee = 0; ee < EPB; ++ee) tepart[g][ee * COUT + c] = accT[ee];
    }
    __syncthreads();

    // ---- reduce partials ----
    {
        float ef = efpart[0][g * COUT + c] + efpart[1][g * COUT + c]
                 + efpart[2][g * COUT + c] + efpart[3][g * COUT + c] + bc[c];
        float te = tepart[0][g * COUT + c] + tepart[1][g * COUT + c]
                 + tepart[2][g * COUT + c] + tepart[3][g * COUT + c] + be[c];
        efs[g][c] = ef;
        teL[g][c] = te;
    }
    __syncthreads();

    // ---- score MLP on threads 0..127 (edge = t>>5, hid = t&31) ----
    if (t < 128) {
        int ee = t >> 5, j = t & 31;
        float hj = eb1[j];
        for (int k = 0; k < COUT; ++k) hj = fmaf(efs[ee][k], eW1[k * HID + j], hj);
        float val = gelu_f(hj) * eW2[j];
#pragma unroll
        for (int m = 16; m >= 1; m >>= 1) val += __shfl_xor(val, m, 32);
        if ((t & 31) == 0) ews[ee] = sigmoid_f(val + eb2[0]);
    }
    __syncthreads();

    // ---- blend + LN ----
    {
        float ew = ews[g];
        float x = efs[g][c] * ew + teL[g][c] * (1.0f - ew);
        float s = x, q = x * x;
#pragma unroll
        for (int m = 32; m >= 1; m >>= 1) { s += __shfl_xor(s, m, 64); q += __shfl_xor(q, m, 64); }
        if (lane == 0) { red[g][gw][0] = s; red[g][gw][1] = q; }
        __syncthreads();
        float S = red[g][0][0] + red[g][1][0];
        float Q = red[g][0][1] + red[g][1][1];
        float m = S * (1.0f / COUT);
        float var = Q * (1.0f / COUT) - m * m;
        float y = (x - m) * rsqrtf(var + EPSV) * ln_g[c] + ln_b[c];
        e_ln[(size_t)e * COUT + c] = y;
    }
}

// ---------------- Kernel 4: BN stats over edges (per channel)
__global__ __launch_bounds__(128) void k_bnstats(const float* __restrict__ e_ln,
    float* __restrict__ bn_sum, float* __restrict__ bn_sq)
{
    int c = threadIdx.x;
    int e0 = blockIdx.x * 16;
    float s = 0, q = 0;
    for (int i = 0; i < 16; ++i) {
        float x = e_ln[(e0 + i) * COUT + c];
        s += x;
        q += x * x;
    }
    atomicAdd(&bn_sum[c], s);
    atomicAdd(&bn_sq[c], q);
}

// ---------------- Kernel 5: BN apply + e_feat output (gelu)
__global__ __launch_bounds__(256) void k_bnapply(const float* __restrict__ e_ln,
    const float* __restrict__ bn_sum, const float* __restrict__ bn_sq,
    const float* __restrict__ bn_g, const float* __restrict__ bn_b,
    float* __restrict__ e_n, float* __restrict__ out_e)
{
    int idx = blockIdx.x * 256 + threadIdx.x;
    int c = idx & 127;
    float m = bn_sum[c] * (1.0f / NE);
    float var = bn_sq[c] * (1.0f / NE) - m * m;
    float x = e_ln[idx];
    float y = (x - m) * rsqrtf(var + EPSV) * bn_g[c] + bn_b[c];
    e_n[idx] = y;
    out_e[idx] = gelu_f(y);
}

// ---------------- Kernel 6: e2v via prebuilt vertex lists + gate + LN + residual + gelu
__global__ __launch_bounds__(512) void k_vertex2(
    const float* __restrict__ X, const int* __restrict__ vdeg, const int* __restrict__ vlist,
    const float* __restrict__ e_n, const float* __restrict__ Xt,
    const float* __restrict__ Wg, const float* __restrict__ bg,
    const float* __restrict__ ln_g, const float* __restrict__ ln_b,
    float* __restrict__ out_v)
{
    __shared__ float Xs[4][CIN];
    __shared__ float vf[4][COUT];
    __shared__ int lst[4][VCAP];
    __shared__ int degs[4];
    __shared__ float red[8][2];
    int t = threadIdx.x;
    int g = t >> 7, c = t & 127;
    int wid = t >> 6;
    int v0 = blockIdx.x * 4;
    int v = v0 + g;

    Xs[g][c] = X[(size_t)v * CIN + c];
    if (c < VCAP) lst[g][c] = vlist[(size_t)v * VCAP + c];
    if (t < 4) degs[t] = vdeg[v0 + t];
    __syncthreads();

    int n = degs[g];
    if (n > VCAP) n = VCAP;
    float acc = 0;
    for (int i = 0; i < n; ++i) acc += e_n[lst[g][i] * COUT + c];
    vf[g][c] = acc;
    __syncthreads();

    float ag = bg[c];
    for (int k = 0; k < CIN; ++k) ag = fmaf(Xs[g][k], Wg[k * COUT + c], ag);
    for (int k = 0; k < COUT; ++k) ag = fmaf(vf[g][k], Wg[(CIN + k) * COUT + c], ag);

    float gate = sigmoid_f(ag);
    float xt = Xt[(size_t)v * COUT + c];
    float x = gate * vf[g][c] + (1.0f - gate) * xt;
    float s = x, q = x * x;
#pragma unroll
    for (int m = 32; m >= 1; m >>= 1) { s += __shfl_xor(s, m, 64); q += __shfl_xor(q, m, 64); }
    if ((t & 63) == 0) { red[wid][0] = s; red[wid][1] = q; }
    __syncthreads();
    float S = red[g * 2][0] + red[g * 2 + 1][0];
    float Q = red[g * 2][1] + red[g * 2 + 1][1];
    float m_ = S * (1.0f / COUT);
    float var = Q * (1.0f / COUT) - m_ * m_;
    float y = (x - m_) * rsqrtf(var + EPSV) * ln_g[c] + ln_b[c];
    y = y + Xs[g][c];
    out_v[(size_t)v * COUT + c] = gelu_f(y);
}

extern "C" void kernel_launch(void* const* d_in, const int* in_sizes, int n_in,
                              void* d_out, int out_size, void* d_ws, size_t ws_size,
                              hipStream_t stream) {
    const float* X    = (const float*)d_in[0];
    const float* H    = (const float*)d_in[1];
    const float* edge_features = (const float*)d_in[2];
    const float* Wv   = (const float*)d_in[3];
    const float* bv   = (const float*)d_in[4];
    const float* We   = (const float*)d_in[5];
    const float* be   = (const float*)d_in[6];
    const float* vW1  = (const float*)d_in[7];
    const float* vb1  = (const float*)d_in[8];
    const float* vW2  = (const float*)d_in[9];
    const float* vb2  = (const float*)d_in[10];
    const float* eW1  = (const float*)d_in[11];
    const float* eb1  = (const float*)d_in[12];
    const float* eW2  = (const float*)d_in[13];
    const float* eb2  = (const float*)d_in[14];
    const float* Wc   = (const float*)d_in[15];
    const float* bc   = (const float*)d_in[16];
    const float* ln_e_g = (const float*)d_in[17];
    const float* ln_e_b = (const float*)d_in[18];
    const float* ln_v_g = (const float*)d_in[19];
    const float* ln_v_b = (const float*)d_in[20];
    const float* bn_g = (const float*)d_in[21];
    const float* bn_b = (const float*)d_in[22];
    const float* Wg   = (const float*)d_in[23];
    const float* bg   = (const float*)d_in[24];

    float* out_v  = (float*)d_out;            // V*COUT
    float* out_e  = out_v + NV * COUT;        // E*COUT
    float* out_att = out_e + NE * COUT;       // E

    char* w = (char*)d_ws;
    float* Xt     = (float*)w; w += (size_t)NV * COUT * 4;
    float* attn4  = (float*)w; w += (size_t)NV * NH * 4;
    float* e_ln   = (float*)w; w += (size_t)NE * COUT * 4;
    float* e_n    = (float*)w; w += (size_t)NE * COUT * 4;
    float* bn_sum = (float*)w; w += COUT * 4;
    float* bn_sq  = (float*)w; w += COUT * 4;
    int*   vdeg   = (int*)w;   w += (size_t)NV * 4;
    int*   vlist  = (int*)w;   w += (size_t)NV * VCAP * 4;
    unsigned long long* Hbits  = (unsigned long long*)w; w += (size_t)NV * NWORDS * 8;
    unsigned long long* HbitsT = (unsigned long long*)w; w += (size_t)NE * TWORDS * 8;

    hipMemsetAsync(bn_sum, 0, 2 * COUT * sizeof(float), stream);

    k_vertex1<<<NV / 8, 128, 0, stream>>>(X, Wv, bv, vW1, vb1, vW2, vb2, Xt, attn4);
    k_build<<<NV / 4, 256, 0, stream>>>(H, Hbits, vdeg, vlist);
    k_transpose<<<NV / 64, 256, 0, stream>>>(Hbits, HbitsT);
    k_edge<<<NE / EPB, 512, 0, stream>>>(Xt, attn4, HbitsT, edge_features,
                                         Wc, bc, We, be, eW1, eb1, eW2, eb2,
                                         ln_e_g, ln_e_b, e_ln, out_att);
    k_bnstats<<<NE / 16, 128, 0, stream>>>(e_ln, bn_sum, bn_sq);
    k_bnapply<<<(NE * COUT) / 256, 256, 0, stream>>>(e_ln, bn_sum, bn_sq, bn_g, bn_b, e_n, out_e);
    k_vertex2<<<NV / 4, 512, 0, stream>>>(X, vdeg, vlist, e_n, Xt, Wg, bg, ln_v_g, ln_v_b, out_v);
}

// Round 7
// 263.564 us; speedup vs baseline: 1.5279x; 1.0842x over previous
//
#include <hip/hip_runtime.h>
#include <hip/hip_bf16.h>
#include <math.h>

#define NV 8192
#define NE 2048
#define CIN 128
#define COUT 128
#define NH 4
#define HID 32
#define EPB 4
#define LCAP 256
#define VCAP 96
#define NWORDS (NE / 64)
#define TWORDS (NV / 64)
#define EPSV 1e-5f

__device__ __forceinline__ float gelu_f(float x) {
    return 0.5f * x * (1.0f + erff(x * 0.70710678118654752f));
}
__device__ __forceinline__ float sigmoid_f(float x) {
    return 1.0f / (1.0f + expf(-x));
}

// ---------------- Kernel A (fused): blocks [0,512) = vertex1 ; blocks [512,2560) = build
__global__ __launch_bounds__(256) void k_front(
    const float* __restrict__ X, const float* __restrict__ Wv, const float* __restrict__ bv,
    const float* __restrict__ vW1, const float* __restrict__ vb1,
    const float* __restrict__ vW2, const float* __restrict__ vb2,
    const float* __restrict__ H,
    float* __restrict__ Xt, float* __restrict__ attn4,
    unsigned long long* __restrict__ Hbits, int* __restrict__ vdeg, int* __restrict__ vlist)
{
    __shared__ float Xs[2][8][CIN];
    int t = threadIdx.x;
    if (blockIdx.x < NV / 16) {
        // ---- vertex1: Xt = X@Wv+bv ; attn ----
        int half = t >> 7, tt = t & 127;
        int v0 = blockIdx.x * 16 + half * 8;
        for (int v = 0; v < 8; ++v) Xs[half][v][tt] = X[(size_t)(v0 + v) * CIN + tt];
        __syncthreads();

        float acc[8];
        float bvc = bv[tt];
#pragma unroll
        for (int v = 0; v < 8; ++v) acc[v] = bvc;
        for (int k = 0; k < CIN; ++k) {
            float w = Wv[k * COUT + tt];
#pragma unroll
            for (int v = 0; v < 8; ++v) acc[v] = fmaf(Xs[half][v][k], w, acc[v]);
        }
        for (int v = 0; v < 8; ++v) Xt[(size_t)(v0 + v) * COUT + tt] = acc[v];

        int h = tt >> 5, j = tt & 31;
        float hb = vb1[h * HID + j];
#pragma unroll
        for (int v = 0; v < 8; ++v) acc[v] = hb;
        for (int k = 0; k < CIN; ++k) {
            float w = vW1[(h * CIN + k) * HID + j];
#pragma unroll
            for (int v = 0; v < 8; ++v) acc[v] = fmaf(Xs[half][v][k], w, acc[v]);
        }
        float w2 = vW2[h * HID + j];
        float b2 = vb2[h];
        for (int v = 0; v < 8; ++v) {
            float val = gelu_f(acc[v]) * w2;
#pragma unroll
            for (int m = 16; m >= 1; m >>= 1) val += __shfl_xor(val, m, 64);
            if (j == 0) attn4[(size_t)(v0 + v) * NH + h] = sigmoid_f(val + b2);
        }
    } else {
        // ---- build: H row scan -> Hbits + per-vertex edge lists (ballot compaction) ----
        int b = blockIdx.x - NV / 16;
        int w = t >> 6;
        int lane = t & 63;
        int v = b * 4 + w;
        const float* row = H + (size_t)v * NE;
        unsigned long long lt = (1ull << lane) - 1ull;
        int base = 0;
        int* vl = vlist + (size_t)v * VCAP;
#pragma unroll 8
        for (int it = 0; it < NWORDS; ++it) {
            float hv = row[it * 64 + lane];
            bool nz = hv != 0.0f;
            unsigned long long m = __ballot(nz);
            if (lane == 0) Hbits[(size_t)v * NWORDS + it] = m;
            if (nz) {
                int pos = base + __popcll(m & lt);
                if (pos < VCAP) vl[pos] = it * 64 + lane;
            }
            base += __popcll(m);
        }
        if (lane == 0) vdeg[v] = base;
    }
}

// ---------------- Kernel 2b: bit-transpose Hbits[v][e-words] -> HbitsT[e][v-words]
__global__ __launch_bounds__(256) void k_transpose(
    const unsigned long long* __restrict__ Hbits, unsigned long long* __restrict__ HbitsT)
{
    __shared__ unsigned long long rows[64][NWORDS];   // 16 KB
    int t = threadIdx.x;
    int vt = blockIdx.x;
    for (int i = t; i < 64 * NWORDS; i += 256)
        rows[i >> 5][i & 31] = Hbits[(size_t)vt * 64 * NWORDS + i];
    __syncthreads();
    int wv = t >> 6;
    int lane = t & 63;
    const unsigned long long M[6] = {
        0xFFFFFFFF00000000ULL, 0xFFFF0000FFFF0000ULL, 0xFF00FF00FF00FF00ULL,
        0xF0F0F0F0F0F0F0F0ULL, 0xCCCCCCCCCCCCCCCCULL, 0xAAAAAAAAAAAAAAAAULL };
    const int js[6] = {32, 16, 8, 4, 2, 1};
#pragma unroll
    for (int itb = 0; itb < 8; ++itb) {
        int it = wv * 8 + itb;
        unsigned long long x = rows[lane][it];
#pragma unroll
        for (int s = 0; s < 6; ++s) {
            int j = js[s];
            unsigned long long y = __shfl_xor(x, j, 64);
            unsigned long long Ms = M[s];
            if ((lane & j) == 0) x = (x & ~Ms) | ((y << j) & Ms);
            else                 x = (x & Ms) | ((y >> j) & ~Ms);
        }
        HbitsT[(size_t)(it * 64 + lane) * TWORDS + vt] = x;
    }
}

// ---------------- Kernel 3: 4 edges/block; 2-wave-split aggregation (each lane covers
// channels lane and lane+64 so both partials are fully written); split-K combine;
// BN stats folded in (block-reduced atomics).
__global__ __launch_bounds__(512) void k_edge(
    const float* __restrict__ Xt, const float* __restrict__ attn4,
    const unsigned long long* __restrict__ HbitsT,
    const float* __restrict__ edge_features,
    const float* __restrict__ Wc, const float* __restrict__ bc,
    const float* __restrict__ We, const float* __restrict__ be,
    const float* __restrict__ eW1, const float* __restrict__ eb1,
    const float* __restrict__ eW2, const float* __restrict__ eb2,
    const float* __restrict__ ln_g, const float* __restrict__ ln_b,
    float* __restrict__ e_ln, float* __restrict__ out_att,
    float* __restrict__ bn_sum, float* __restrict__ bn_sq)
{
    __shared__ int lst[EPB][LCAP];
    __shared__ int wsum[EPB][2];
    __shared__ float scratch[4096];        // 16 KB, phase-aliased
    __shared__ float ecat[EPB][NH * COUT];
    __shared__ float efr_s[EPB][COUT];
    __shared__ float efs[EPB][COUT];
    __shared__ float teL[EPB][COUT];
    __shared__ float ews[EPB];
    __shared__ float asp[EPB][2];
    __shared__ float red[EPB][2][2];

    int t = threadIdx.x;
    int g = t >> 7;           // group = edge slot
    int c = t & 127;
    int lane = t & 63;
    int gw = (t >> 6) & 1;    // wave within group
    int e = blockIdx.x * EPB + g;

    efr_s[g][c] = edge_features[(size_t)e * COUT + c];

    // ---- membership: coalesced bitmap row + scan compaction ----
    unsigned long long wd = HbitsT[(size_t)e * TWORDS + c];
    int cntT = __popcll(wd);
    int inc = cntT;
#pragma unroll
    for (int s = 1; s < 64; s <<= 1) {
        int y = __shfl_up(inc, s, 64);
        if (lane >= s) inc += y;
    }
    if (lane == 63) wsum[g][gw] = inc;
    __syncthreads();
    int base = (gw ? wsum[g][0] : 0) + inc - cntT;
    int n0 = wsum[g][0] + wsum[g][1];
    int vbase = c * 64;
    unsigned long long mm = wd;
    while (mm) {
        int i = __ffsll(mm) - 1;
        mm &= mm - 1;
        if (base < LCAP) lst[g][base] = vbase + i;
        ++base;
    }
    __syncthreads();

    float inv = 1.0f / fmaxf((float)n0, 1.0f);
    int n = n0 < LCAP ? n0 : LCAP;

    // ---- aggregation: two waves split the member list; lane l covers channels l, l+64 ----
    float p00 = 0, p10 = 0, p20 = 0, p30 = 0;   // channel = lane
    float p01 = 0, p11 = 0, p21 = 0, p31 = 0;   // channel = lane + 64
    float as = 0;
    for (int i = gw; i < n; i += 2) {
        int v = lst[g][i];
        float x0 = Xt[(size_t)v * COUT + lane];
        float x1 = Xt[(size_t)v * COUT + lane + 64];
        float4 a = *(const float4*)(attn4 + (size_t)v * NH);
        p00 = fmaf(x0, a.x, p00);  p01 = fmaf(x1, a.x, p01);
        p10 = fmaf(x0, a.y, p10);  p11 = fmaf(x1, a.y, p11);
        p20 = fmaf(x0, a.z, p20);  p21 = fmaf(x1, a.z, p21);
        p30 = fmaf(x0, a.w, p30);  p31 = fmaf(x1, a.w, p31);
        as += a.w;
    }
    {
        int bi = (g * 2 + gw) * NH * COUT;
        scratch[bi + 0 * COUT + lane] = p00;  scratch[bi + 0 * COUT + lane + 64] = p01;
        scratch[bi + 1 * COUT + lane] = p10;  scratch[bi + 1 * COUT + lane + 64] = p11;
        scratch[bi + 2 * COUT + lane] = p20;  scratch[bi + 2 * COUT + lane + 64] = p21;
        scratch[bi + 3 * COUT + lane] = p30;  scratch[bi + 3 * COUT + lane + 64] = p31;
    }
    if (lane == 0) asp[g][gw] = as;
    __syncthreads();

#pragma unroll
    for (int h = 0; h < NH; ++h)
        ecat[g][h * COUT + c] =
            (scratch[(g * 2 + 0) * NH * COUT + h * COUT + c] +
             scratch[(g * 2 + 1) * NH * COUT + h * COUT + c]) * inv;
    if (c == 0) out_att[e] = (asp[g][0] + asp[g][1]) * inv;
    __syncthreads();

    // ---- split-K combine, weights shared across 4 edges ----
    {
        float accW[EPB] = {0, 0, 0, 0};
        const float* wp = Wc + (size_t)(g * 128) * COUT + c;
        for (int k = 0; k < 128; ++k) {
            float w = wp[k * COUT];
#pragma unroll
            for (int ee = 0; ee < EPB; ++ee)
                accW[ee] = fmaf(ecat[ee][g * 128 + k], w, accW[ee]);
        }
#pragma unroll
        for (int ee = 0; ee < EPB; ++ee) scratch[g * 512 + ee * COUT + c] = accW[ee];

        float accT[EPB] = {0, 0, 0, 0};
        const float* wt = We + (size_t)(g * 32) * COUT + c;
        for (int k = 0; k < 32; ++k) {
            float w = wt[k * COUT];
#pragma unroll
            for (int ee = 0; ee < EPB; ++ee)
                accT[ee] = fmaf(efr_s[ee][g * 32 + k], w, accT[ee]);
        }
#pragma unroll
        for (int ee = 0; ee < EPB; ++ee) scratch[2048 + g * 512 + ee * COUT + c] = accT[ee];
    }
    __syncthreads();

    // ---- reduce partials ----
    efs[g][c] = scratch[0 * 512 + g * COUT + c] + scratch[1 * 512 + g * COUT + c]
              + scratch[2 * 512 + g * COUT + c] + scratch[3 * 512 + g * COUT + c] + bc[c];
    teL[g][c] = scratch[2048 + 0 * 512 + g * COUT + c] + scratch[2048 + 1 * 512 + g * COUT + c]
              + scratch[2048 + 2 * 512 + g * COUT + c] + scratch[2048 + 3 * 512 + g * COUT + c] + be[c];
    __syncthreads();

    // ---- score MLP on threads 0..127 ----
    if (t < 128) {
        int ee = t >> 5, j = t & 31;
        float hj = eb1[j];
        for (int k = 0; k < COUT; ++k) hj = fmaf(efs[ee][k], eW1[k * HID + j], hj);
        float val = gelu_f(hj) * eW2[j];
#pragma unroll
        for (int m = 16; m >= 1; m >>= 1) val += __shfl_xor(val, m, 32);
        if ((t & 31) == 0) ews[ee] = sigmoid_f(val + eb2[0]);
    }
    __syncthreads();

    // ---- blend + LN + BN partials ----
    float y;
    {
        float ew = ews[g];
        float x = efs[g][c] * ew + teL[g][c] * (1.0f - ew);
        float s = x, q = x * x;
#pragma unroll
        for (int m = 32; m >= 1; m >>= 1) { s += __shfl_xor(s, m, 64); q += __shfl_xor(q, m, 64); }
        if (lane == 0) { red[g][gw][0] = s; red[g][gw][1] = q; }
        __syncthreads();
        float S = red[g][0][0] + red[g][1][0];
        float Q = red[g][0][1] + red[g][1][1];
        float m = S * (1.0f / COUT);
        float var = Q * (1.0f / COUT) - m * m;
        y = (x - m) * rsqrtf(var + EPSV) * ln_g[c] + ln_b[c];
        e_ln[(size_t)e * COUT + c] = y;
    }
    scratch[g * COUT + c] = y;
    scratch[512 + g * COUT + c] = y * y;
    __syncthreads();
    if (t < 128) {
        float s = scratch[t] + scratch[COUT + t] + scratch[2 * COUT + t] + scratch[3 * COUT + t];
        float q = scratch[512 + t] + scratch[512 + COUT + t] + scratch[512 + 2 * COUT + t] + scratch[512 + 3 * COUT + t];
        atomicAdd(&bn_sum[t], s);
        atomicAdd(&bn_sq[t], q);
    }
}

// ---------------- Kernel 5: BN apply -> out_e (gelu) only
__global__ __launch_bounds__(256) void k_bnapply(const float* __restrict__ e_ln,
    const float* __restrict__ bn_sum, const float* __restrict__ bn_sq,
    const float* __restrict__ bn_g, const float* __restrict__ bn_b,
    float* __restrict__ out_e)
{
    int idx = blockIdx.x * 256 + threadIdx.x;
    int c = idx & 127;
    float m = bn_sum[c] * (1.0f / NE);
    float var = bn_sq[c] * (1.0f / NE) - m * m;
    float x = e_ln[idx];
    float y = (x - m) * rsqrtf(var + EPSV) * bn_g[c] + bn_b[c];
    out_e[idx] = gelu_f(y);
}

// ---------------- Kernel 6: e2v gather (BN folded: A*sum + n*B) + gate GEMM (split-K,
// weights shared across 8 vertices) + LN + residual + gelu. 512 thr, 8 vertices/block.
__global__ __launch_bounds__(512) void k_vertex2(
    const float* __restrict__ X, const int* __restrict__ vdeg, const int* __restrict__ vlist,
    const float* __restrict__ e_ln,
    const float* __restrict__ bn_sum, const float* __restrict__ bn_sq,
    const float* __restrict__ bn_g, const float* __restrict__ bn_b,
    const float* __restrict__ Xt,
    const float* __restrict__ Wg, const float* __restrict__ bg,
    const float* __restrict__ ln_g, const float* __restrict__ ln_b,
    float* __restrict__ out_v)
{
    __shared__ float XsF[8 * CIN];     // 4 KB
    __shared__ float vfF[8 * COUT];    // 4 KB
    __shared__ int lst[8][VCAP];       // 3 KB
    __shared__ int degs[8];
    __shared__ float part[4 * 8 * COUT]; // 16 KB
    __shared__ float red[8][2][2];

    int t = threadIdx.x;
    int vg = t >> 6, lane = t & 63;
    int g4 = t >> 7, c = t & 127;
    int gw2 = (t >> 6) & 1;
    int v0 = blockIdx.x * 8;

    // stage X rows (float2 per lane)
    {
        float2 x2 = *(const float2*)(X + (size_t)(v0 + vg) * CIN + lane * 2);
        XsF[vg * CIN + lane * 2] = x2.x;
        XsF[vg * CIN + lane * 2 + 1] = x2.y;
    }
    for (int i = t; i < 8 * VCAP; i += 512)
        lst[i / VCAP][i % VCAP] = vlist[(size_t)v0 * VCAP + i];
    if (t < 8) degs[t] = vdeg[v0 + t];
    __syncthreads();

    // BN affine for this thread's two channels
    int ch0 = lane * 2;
    float m0 = bn_sum[ch0] * (1.0f / NE);
    float m1 = bn_sum[ch0 + 1] * (1.0f / NE);
    float A0 = bn_g[ch0] * rsqrtf(bn_sq[ch0] * (1.0f / NE) - m0 * m0 + EPSV);
    float A1 = bn_g[ch0 + 1] * rsqrtf(bn_sq[ch0 + 1] * (1.0f / NE) - m1 * m1 + EPSV);
    float B0 = bn_b[ch0] - m0 * A0;
    float B1 = bn_b[ch0 + 1] - m1 * A1;

    // gather raw sums, then apply BN algebraically
    int n = degs[vg];
    if (n > VCAP) n = VCAP;
    float sx = 0, sy = 0;
    for (int i = 0; i < n; ++i) {
        float2 v2 = *(const float2*)(e_ln + (size_t)lst[vg][i] * COUT + ch0);
        sx += v2.x;
        sy += v2.y;
    }
    float fn = (float)n;
    vfF[vg * COUT + ch0] = A0 * sx + fn * B0;
    vfF[vg * COUT + ch0 + 1] = A1 * sy + fn * B1;
    __syncthreads();

    // gate GEMM: split-K (4 groups x 64 steps), weight shared across 8 vertices
    {
        float accW[8] = {0, 0, 0, 0, 0, 0, 0, 0};
        const float* wp = Wg + (size_t)(g4 * 64) * COUT + c;
        const float* src = (g4 < 2) ? XsF : vfF;
        int kb = (g4 & 1) * 64;
        for (int ki = 0; ki < 64; ++ki) {
            float w = wp[(size_t)ki * COUT];
#pragma unroll
            for (int v = 0; v < 8; ++v)
                accW[v] = fmaf(src[v * 128 + kb + ki], w, accW[v]);
        }
#pragma unroll
        for (int v = 0; v < 8; ++v) part[g4 * 1024 + v * COUT + c] = accW[v];
    }
    __syncthreads();

    // reduce + gate + LN + residual + gelu (each group handles vertices g4 and g4+4)
    float xv[2];
#pragma unroll
    for (int rep = 0; rep < 2; ++rep) {
        int v = g4 + rep * 4;
        float ag = part[0 * 1024 + v * COUT + c] + part[1 * 1024 + v * COUT + c]
                 + part[2 * 1024 + v * COUT + c] + part[3 * 1024 + v * COUT + c] + bg[c];
        float gate = sigmoid_f(ag);
        float x = gate * vfF[v * COUT + c] + (1.0f - gate) * Xt[(size_t)(v0 + v) * COUT + c];
        xv[rep] = x;
        float s = x, q = x * x;
#pragma unroll
        for (int m = 32; m >= 1; m >>= 1) { s += __shfl_xor(s, m, 64); q += __shfl_xor(q, m, 64); }
        if (lane == 0) { red[v][gw2][0] = s; red[v][gw2][1] = q; }
    }
    __syncthreads();
#pragma unroll
    for (int rep = 0; rep < 2; ++rep) {
        int v = g4 + rep * 4;
        float S = red[v][0][0] + red[v][1][0];
        float Q = red[v][0][1] + red[v][1][1];
        float m_ = S * (1.0f / COUT);
        float var = Q * (1.0f / COUT) - m_ * m_;
        float y = (xv[rep] - m_) * rsqrtf(var + EPSV) * ln_g[c] + ln_b[c];
        y = y + XsF[v * CIN + c];
        out_v[(size_t)(v0 + v) * COUT + c] = gelu_f(y);
    }
}

extern "C" void kernel_launch(void* const* d_in, const int* in_sizes, int n_in,
                              void* d_out, int out_size, void* d_ws, size_t ws_size,
                              hipStream_t stream) {
    const float* X    = (const float*)d_in[0];
    const float* H    = (const float*)d_in[1];
    const float* edge_features = (const float*)d_in[2];
    const float* Wv   = (const float*)d_in[3];
    const float* bv   = (const float*)d_in[4];
    const float* We   = (const float*)d_in[5];
    const float* be   = (const float*)d_in[6];
    const float* vW1  = (const float*)d_in[7];
    const float* vb1  = (const float*)d_in[8];
    const float* vW2  = (const float*)d_in[9];
    const float* vb2  = (const float*)d_in[10];
    const float* eW1  = (const float*)d_in[11];
    const float* eb1  = (const float*)d_in[12];
    const float* eW2  = (const float*)d_in[13];
    const float* eb2  = (const float*)d_in[14];
    const float* Wc   = (const float*)d_in[15];
    const float* bc   = (const float*)d_in[16];
    const float* ln_e_g = (const float*)d_in[17];
    const float* ln_e_b = (const float*)d_in[18];
    const float* ln_v_g = (const float*)d_in[19];
    const float* ln_v_b = (const float*)d_in[20];
    const float* bn_g = (const float*)d_in[21];
    const float* bn_b = (const float*)d_in[22];
    const float* Wg   = (const float*)d_in[23];
    const float* bg   = (const float*)d_in[24];

    float* out_v  = (float*)d_out;            // V*COUT
    float* out_e  = out_v + NV * COUT;        // E*COUT
    float* out_att = out_e + NE * COUT;       // E

    char* w = (char*)d_ws;
    float* Xt     = (float*)w; w += (size_t)NV * COUT * 4;
    float* attn4  = (float*)w; w += (size_t)NV * NH * 4;
    float* e_ln   = (float*)w; w += (size_t)NE * COUT * 4;
    float* bn_sum = (float*)w; w += COUT * 4;
    float* bn_sq  = (float*)w; w += COUT * 4;
    int*   vdeg   = (int*)w;   w += (size_t)NV * 4;
    int*   vlist  = (int*)w;   w += (size_t)NV * VCAP * 4;
    unsigned long long* Hbits  = (unsigned long long*)w; w += (size_t)NV * NWORDS * 8;
    unsigned long long* HbitsT = (unsigned long long*)w; w += (size_t)NE * TWORDS * 8;

    hipMemsetAsync(bn_sum, 0, 2 * COUT * sizeof(float), stream);

    k_front<<<NV / 16 + NV / 4, 256, 0, stream>>>(X, Wv, bv, vW1, vb1, vW2, vb2, H,
                                                  Xt, attn4, Hbits, vdeg, vlist);
    k_transpose<<<NV / 64, 256, 0, stream>>>(Hbits, HbitsT);
    k_edge<<<NE / EPB, 512, 0, stream>>>(Xt, attn4, HbitsT, edge_features,
                                         Wc, bc, We, be, eW1, eb1, eW2, eb2,
                                         ln_e_g, ln_e_b, e_ln, out_att, bn_sum, bn_sq);
    k_bnapply<<<(NE * COUT) / 256, 256, 0, stream>>>(e_ln, bn_sum, bn_sq, bn_g, bn_b, out_e);
    k_vertex2<<<NV / 8, 512, 0, stream>>>(X, vdeg, vlist, e_ln, bn_sum, bn_sq, bn_g, bn_b,
                                          Xt, Wg, bg, ln_v_g, ln_v_b, out_v);
}